// Round 16
// baseline (975.144 us; speedup 1.0000x reference)
//
#include <hip/hip_runtime.h>

#define N_NODES 50000
#define M_PAD 50048      // N_NODES rounded up to 128
#define N_EDGES 500000
#define HEADS 6
#define CH 64
#define F_HID 384
#define IN_DIM 131
#define K0PAD 160        // layer-0 K padded to multiple of 32
#define CAP 64           // fast-path max degree
#define NBM 391          // cdiv(N_NODES,128)
#define ATILE3 98304     // (384/32)*8192 bytes per 128-row fp16 A tile
#define ATILE0 40960     // (160/32)*8192
#define BTILE3 98304     // (384/32)*8192 per 128-col fp16 B tile
#define BTILE0 40960

static inline int cdiv(int a, int b) { return (a + b - 1) / b; }

typedef __attribute__((ext_vector_type(4))) float f32x4;
typedef __attribute__((ext_vector_type(8))) _Float16 f16x8;
typedef __attribute__((ext_vector_type(4))) _Float16 f16x4;

__device__ __forceinline__ void gload16(const void* g, void* lds) {
  __builtin_amdgcn_global_load_lds((const __attribute__((address_space(1))) void*)g,
                                   (__attribute__((address_space(3))) void*)lds, 16, 0, 0);
}

// ---------------- CSR build ----------------
__global__ void count_kernel(const int* __restrict__ ei, int* __restrict__ deg) {
  int e = blockIdx.x * blockDim.x + threadIdx.x;
  if (e < N_EDGES) atomicAdd(&deg[ei[N_EDGES + e]], 1);
}

// writes both off (exclusive prefix, +1 shifted) and cur (= off[i], scatter cursors)
__global__ void scan_kernel(const int* __restrict__ deg, int* __restrict__ off,
                            int* __restrict__ cur) {
  __shared__ int sdata[256];
  int tid = threadIdx.x;
  int carry = 0;
  if (tid == 0) off[0] = 0;
  for (int base = 0; base < N_NODES; base += 1024) {
    int idx0 = base + tid * 4;
    int v[4]; int s = 0;
#pragma unroll
    for (int j = 0; j < 4; j++) {
      v[j] = (idx0 + j < N_NODES) ? deg[idx0 + j] : 0;
      s += v[j];
    }
    sdata[tid] = s;
    __syncthreads();
    for (int o = 1; o < 256; o <<= 1) {
      int x = (tid >= o) ? sdata[tid - o] : 0;
      __syncthreads();
      sdata[tid] += x;
      __syncthreads();
    }
    int excl = sdata[tid] - s + carry;
    int total = sdata[255];
    int run = excl;
#pragma unroll
    for (int j = 0; j < 4; j++) {
      if (idx0 + j < N_NODES) cur[idx0 + j] = run;
      run += v[j];
      if (idx0 + j < N_NODES) off[idx0 + j + 1] = run;
    }
    carry += total;
    __syncthreads();
  }
}

__global__ void scatter_kernel(const int* __restrict__ ei, int* __restrict__ cursor,
                               int* __restrict__ csr_src) {
  int e = blockIdx.x * blockDim.x + threadIdx.x;
  if (e < N_EDGES) {
    int d = ei[N_EDGES + e];
    int p = atomicAdd(&cursor[d], 1);
    csr_src[p] = ei[e];
  }
}

// ---------------- degree bucketing: order[] = nodes sorted by degree (desc) ----
__global__ void bucket_hist(const int* __restrict__ deg, int* __restrict__ hcnt) {
  int n = blockIdx.x * blockDim.x + threadIdx.x;
  if (n < N_NODES) {
    int b = 63 - min(deg[n], 63);  // descending degree
    atomicAdd(&hcnt[b], 1);
  }
}

__global__ void bucket_scan(const int* __restrict__ hcnt, int* __restrict__ hcur) {
  int t = threadIdx.x;  // 64 threads, one wave
  int c = hcnt[t];
  int v = c;
#pragma unroll
  for (int o = 1; o < 64; o <<= 1) {
    int u = __shfl_up(v, o);
    if (t >= o) v += u;
  }
  hcur[t] = v - c;  // exclusive prefix
}

__global__ void bucket_scatter(const int* __restrict__ deg, int* __restrict__ hcur,
                               int* __restrict__ order) {
  int n = blockIdx.x * blockDim.x + threadIdx.x;
  if (n < N_NODES) {
    int b = 63 - min(deg[n], 63);
    int p = atomicAdd(&hcur[b], 1);
    order[p] = n;
  }
}

// ---------------- unified packer (chunk-major layout) ----------------
#define NXITEMS (M_PAD * (K0PAD / 8))
#define NW0ITEMS (F_HID * (K0PAD / 8))
#define NWITEMS (F_HID * (F_HID / 8))
__global__ void convert_all(const float* __restrict__ x, const float* __restrict__ W0,
                            const float* __restrict__ W1, const float* __restrict__ W2,
                            const float* __restrict__ W3, char* __restrict__ Apk,
                            char* __restrict__ Wt0, char* __restrict__ Wt1,
                            char* __restrict__ Wt2, char* __restrict__ Wt3) {
  int t = blockIdx.x * blockDim.x + threadIdx.x;
  if (t < NXITEMS) {
    const int npc = K0PAD / 8;
    int r = t / npc, g = t % npc;
    int kt = g >> 2, kb = g & 3;
    int k0 = kt * 32 + kb * 8;
    f16x8 hv;
#pragma unroll
    for (int j = 0; j < 8; j++) {
      int k = k0 + j;
      float v = (r < N_NODES && k < IN_DIM) ? x[(long)r * IN_DIM + k] : 0.0f;
      hv[j] = (_Float16)v;
    }
    *(f16x8*)(Apk + (size_t)(r >> 7) * ATILE0 + kt * 8192 + kb * 2048 + (r & 127) * 16) = hv;
  } else if (t < NXITEMS + NW0ITEMS) {
    int u = t - NXITEMS;
    const int npc = K0PAD >> 3;
    int n = u / npc, g = u % npc;
    int kt = g >> 2, kb = g & 3;
    int k0 = kt * 32 + kb * 8;
    f16x8 hv;
#pragma unroll
    for (int j = 0; j < 8; j++) {
      int k = k0 + j;
      float v = (k < IN_DIM) ? W0[(long)k * F_HID + n] : 0.0f;
      hv[j] = (_Float16)v;
    }
    *(f16x8*)(Wt0 + (size_t)(n >> 7) * BTILE0 + kt * 8192 + kb * 2048 + (n & 127) * 16) = hv;
  } else if (t < NXITEMS + NW0ITEMS + 3 * NWITEMS) {
    int u = t - NXITEMS - NW0ITEMS;
    int l = u / NWITEMS;
    u -= l * NWITEMS;
    const float* W = l == 0 ? W1 : (l == 1 ? W2 : W3);
    char* Wt = l == 0 ? Wt1 : (l == 1 ? Wt2 : Wt3);
    const int npc = F_HID >> 3;
    int n = u / npc, g = u % npc;
    int kt = g >> 2, kb = g & 3;
    int k0 = kt * 32 + kb * 8;
    f16x8 hv;
#pragma unroll
    for (int j = 0; j < 8; j++) hv[j] = (_Float16)W[(long)(k0 + j) * F_HID + n];
    *(f16x8*)(Wt + (size_t)(n >> 7) * BTILE3 + kt * 8192 + kb * 2048 + (n & 127) * 16) = hv;
  }
}

// ---------------- fp16 MFMA GEMM + fused attention dots ----------------
template <int K>
__global__ __launch_bounds__(256) void gemm_mfma(const char* __restrict__ Ap,
                                                 const char* __restrict__ Bp,
                                                 const float* __restrict__ AS,
                                                 const float* __restrict__ AD,
                                                 float* __restrict__ als,
                                                 float* __restrict__ ald,
                                                 _Float16* __restrict__ O) {
  constexpr int NKT = K / 32;
  __shared__ __align__(16) char smA[8192];
  __shared__ __align__(16) char smB[8192];
  int xcd = blockIdx.x & 7, slot = blockIdx.x >> 3;
  int bn = slot % 3, tt = slot / 3;
  int bm = tt * 8 + xcd;
  if (bm >= NBM) return;
  int row0 = bm * 128, col0 = bn * 128;
  int tid = threadIdx.x, lane = tid & 63, wv = tid >> 6;
  int wy = wv >> 1, wx = wv & 1;

  f32x4 acc[4][4];
#pragma unroll
  for (int i = 0; i < 4; i++)
#pragma unroll
    for (int j = 0; j < 4; j++) acc[i][j] = (f32x4)0.0f;

  const char* Ab = Ap + (size_t)bm * (NKT * 8192);
  const char* Bb = Bp + (size_t)bn * (NKT * 8192);
  int rsel = lane & 15, ksel = lane >> 4;

  for (int kt = 0; kt < NKT; ++kt) {
#pragma unroll
    for (int i = 0; i < 2; ++i) {
      int b = (i * 4 + wv) * 1024;
      gload16(Ab + (size_t)kt * 8192 + b + lane * 16, smA + b);
      gload16(Bb + (size_t)kt * 8192 + b + lane * 16, smB + b);
    }
    __syncthreads();

    f16x8 av[4], bv[4];
#pragma unroll
    for (int mf = 0; mf < 4; ++mf)
      av[mf] = *(const f16x8*)(smA + ksel * 2048 + (wy * 64 + mf * 16 + rsel) * 16);
#pragma unroll
    for (int nf = 0; nf < 4; ++nf)
      bv[nf] = *(const f16x8*)(smB + ksel * 2048 + (wx * 64 + nf * 16 + rsel) * 16);
#pragma unroll
    for (int mf = 0; mf < 4; ++mf)
#pragma unroll
      for (int nf = 0; nf < 4; ++nf)
        acc[mf][nf] = __builtin_amdgcn_mfma_f32_16x16x32_f16(av[mf], bv[nf], acc[mf][nf], 0, 0, 0);
    __syncthreads();
  }

  int cr = (lane >> 4) * 4, cc = lane & 15;
#pragma unroll
  for (int mf = 0; mf < 4; ++mf)
#pragma unroll
    for (int r = 0; r < 4; ++r) {
      int row = row0 + wy * 64 + mf * 16 + cr + r;
      if (row < N_NODES) {
#pragma unroll
        for (int nf = 0; nf < 4; ++nf)
          O[(size_t)row * F_HID + col0 + wx * 64 + nf * 16 + cc] = (_Float16)acc[mf][nf][r];
      }
    }
  // fused dots: head = 2*bn + wx; this wave holds its full 64 cols
  int head = bn * 2 + wx;
  float sa[4], da[4];
#pragma unroll
  for (int nf = 0; nf < 4; ++nf) {
    sa[nf] = AS[head * CH + nf * 16 + cc];
    da[nf] = AD[head * CH + nf * 16 + cc];
  }
#pragma unroll
  for (int mf = 0; mf < 4; ++mf)
#pragma unroll
    for (int r = 0; r < 4; ++r) {
      float ps = 0.0f, pd = 0.0f;
#pragma unroll
      for (int nf = 0; nf < 4; ++nf) {
        ps += acc[mf][nf][r] * sa[nf];
        pd += acc[mf][nf][r] * da[nf];
      }
#pragma unroll
      for (int o = 1; o < 16; o <<= 1) {
        ps += __shfl_xor(ps, o);
        pd += __shfl_xor(pd, o);
      }
      int row = row0 + wy * 64 + mf * 16 + cr + r;
      if (cc == 0 && row < N_NODES) {
        als[row * HEADS + head] = ps;
        ald[row * HEADS + head] = pd;
      }
    }
}

// ---------------- fused-AB agg core (R13-proven) + degree-sorted node order ----
typedef __attribute__((ext_vector_type(4))) _Float16 f16x4t;
#define AGG_CORE(FEAT, OFF, CSR, ALS, ALD, ORD)                                   \
  int tid = threadIdx.x;                                                          \
  int sub = tid / 96, t96 = tid - sub * 96;                                       \
  int nb = blockIdx.x * 4;                                                        \
  int n = ORD[nb + sub];                                                          \
  int c4 = t96 * 4, h = t96 >> 4;                                                 \
  int dmax = 0;                                                                   \
  _Pragma("unroll")                                                               \
  for (int k = 0; k < 4; ++k) {                                                   \
    int nn = ORD[nb + k];                                                         \
    dmax = max(dmax, OFF[nn + 1] - OFF[nn]);                                      \
  }                                                                               \
  int nch = (dmax + CAP - 1) / CAP; if (nch < 1) nch = 1;                         \
  int s0 = OFF[n], deg = OFF[n + 1] - s0;                                         \
  int pr = tid >> 4, pl = tid & 15;                                               \
  int psub = pr / 6, ph = pr - psub * 6;                                          \
  int pn = ORD[nb + psub];                                                        \
  int ps0 = OFF[pn], pdeg = OFF[pn + 1] - ps0;                                    \
  float pad_ = ALD[pn * 6 + ph];                                                  \
  float m_run = -INFINITY, s_run = 0.0f;                                          \
  float a0 = 0, a1 = 0, a2 = 0, a3 = 0;                                           \
  for (int ch = 0; ch < nch; ++ch) {                                              \
    int base = ch * CAP;                                                          \
    int cl = deg - base; cl = cl < 0 ? 0 : (cl > CAP ? CAP : cl);                 \
    if (t96 < cl) lsrc[sub][t96] = CSR[s0 + base + t96];                          \
    int pcl = pdeg - base; pcl = pcl < 0 ? 0 : (pcl > CAP ? CAP : pcl);           \
    float asc = 1.0f;                                                             \
    if (pcl > 0) {                                                                \
      float mc = -INFINITY;                                                       \
      for (int i = pl; i < pcl; i += 16) {                                        \
        int s = CSR[ps0 + base + i];                                              \
        float e = ALS[s * 6 + ph] + pad_;                                         \
        e = e > 0.0f ? e : 0.2f * e;                                              \
        lew[psub][ph][i] = e;                                                     \
        mc = fmaxf(mc, e);                                                        \
      }                                                                           \
      mc = fmaxf(mc, __shfl_xor(mc, 1));                                          \
      mc = fmaxf(mc, __shfl_xor(mc, 2));                                          \
      mc = fmaxf(mc, __shfl_xor(mc, 4));                                          \
      mc = fmaxf(mc, __shfl_xor(mc, 8));                                          \
      float mn = fmaxf(m_run, mc);                                                \
      asc = (m_run == -INFINITY) ? 0.0f : __expf(m_run - mn);                     \
      float scp = 0.0f;                                                           \
      for (int i = pl; i < pcl; i += 16) {                                        \
        float wv = __expf(lew[psub][ph][i] - mn);                                 \
        lew[psub][ph][i] = wv;                                                    \
        scp += wv;                                                                \
      }                                                                           \
      scp += __shfl_xor(scp, 1);                                                  \
      scp += __shfl_xor(scp, 2);                                                  \
      scp += __shfl_xor(scp, 4);                                                  \
      scp += __shfl_xor(scp, 8);                                                  \
      s_run = s_run * asc + scp;                                                  \
      m_run = mn;                                                                 \
    }                                                                             \
    if (pl == 0) {                                                                \
      lasc[psub][ph] = asc;                                                       \
      if (ch == nch - 1) lrr[psub][ph] = 1.0f / (s_run + 1e-16f);                 \
    }                                                                             \
    __syncthreads();                                                              \
    float cc0 = 0, cc1 = 0, cc2 = 0, cc3 = 0;                                     \
    int i = 0;                                                                    \
    for (; i + 4 <= cl; i += 4) {                                                 \
      int sA = lsrc[sub][i], sB = lsrc[sub][i + 1];                               \
      int sC = lsrc[sub][i + 2], sD = lsrc[sub][i + 3];                           \
      float wA = lew[sub][h][i], wB = lew[sub][h][i + 1];                         \
      float wC = lew[sub][h][i + 2], wD = lew[sub][h][i + 3];                     \
      f16x4t fA = *(const f16x4t*)(FEAT + (size_t)sA * F_HID + c4);               \
      f16x4t fB = *(const f16x4t*)(FEAT + (size_t)sB * F_HID + c4);               \
      f16x4t fC = *(const f16x4t*)(FEAT + (size_t)sC * F_HID + c4);               \
      f16x4t fD = *(const f16x4t*)(FEAT + (size_t)sD * F_HID + c4);               \
      cc0 += wA * (float)fA[0]; cc1 += wA * (float)fA[1];                         \
      cc2 += wA * (float)fA[2]; cc3 += wA * (float)fA[3];                         \
      cc0 += wB * (float)fB[0]; cc1 += wB * (float)fB[1];                         \
      cc2 += wB * (float)fB[2]; cc3 += wB * (float)fB[3];                         \
      cc0 += wC * (float)fC[0]; cc1 += wC * (float)fC[1];                         \
      cc2 += wC * (float)fC[2]; cc3 += wC * (float)fC[3];                         \
      cc0 += wD * (float)fD[0]; cc1 += wD * (float)fD[1];                         \
      cc2 += wD * (float)fD[2]; cc3 += wD * (float)fD[3];                         \
    }                                                                             \
    for (; i < cl; ++i) {                                                         \
      int s = lsrc[sub][i];                                                       \
      float wv = lew[sub][h][i];                                                  \
      f16x4t fv = *(const f16x4t*)(FEAT + (size_t)s * F_HID + c4);                \
      cc0 += wv * (float)fv[0]; cc1 += wv * (float)fv[1];                         \
      cc2 += wv * (float)fv[2]; cc3 += wv * (float)fv[3];                         \
    }                                                                             \
    float asc2 = lasc[sub][h];                                                    \
    a0 = a0 * asc2 + cc0; a1 = a1 * asc2 + cc1;                                   \
    a2 = a2 * asc2 + cc2; a3 = a3 * asc2 + cc3;                                   \
    __syncthreads();                                                              \
  }                                                                               \
  float rr = lrr[sub][h];

// hidden layers: normalize + bias + ELU + fp16 pack (chunk-major A plane)
__global__ __launch_bounds__(384) void agg_hidden(const _Float16* __restrict__ feat,
                                                  const int* __restrict__ off,
                                                  const int* __restrict__ csr_src,
                                                  const float* __restrict__ al_s,
                                                  const float* __restrict__ al_d,
                                                  const float* __restrict__ bias,
                                                  const int* __restrict__ order,
                                                  char* __restrict__ Apk) {
  __shared__ int   lsrc[4][CAP + 1];
  __shared__ float lew[4][6][CAP + 1];
  __shared__ float lasc[4][6];
  __shared__ float lrr[4][6];
  AGG_CORE(feat, off, csr_src, al_s, al_d, order)
  float v0 = a0 * rr + bias[c4 + 0];
  float v1 = a1 * rr + bias[c4 + 1];
  float v2 = a2 * rr + bias[c4 + 2];
  float v3 = a3 * rr + bias[c4 + 3];
  v0 = v0 > 0.0f ? v0 : (__expf(v0) - 1.0f);
  v1 = v1 > 0.0f ? v1 : (__expf(v1) - 1.0f);
  v2 = v2 > 0.0f ? v2 : (__expf(v2) - 1.0f);
  v3 = v3 > 0.0f ? v3 : (__expf(v3) - 1.0f);
  f16x4 pv;
  pv[0] = (_Float16)v0; pv[1] = (_Float16)v1;
  pv[2] = (_Float16)v2; pv[3] = (_Float16)v3;
  int kt = c4 >> 5, kb = (c4 >> 3) & 3;
  *(f16x4*)(Apk + (size_t)(n >> 7) * ATILE3 + kt * 8192 + kb * 2048 +
            (n & 127) * 16 + (c4 & 7) * 2) = pv;
}

// output layer: normalize + head-mean + bias
__global__ __launch_bounds__(384) void agg_out(const _Float16* __restrict__ feat,
                                               const int* __restrict__ off,
                                               const int* __restrict__ csr_src,
                                               const float* __restrict__ al_s,
                                               const float* __restrict__ al_d,
                                               const float* __restrict__ b3,
                                               const int* __restrict__ order,
                                               float* __restrict__ out) {
  __shared__ int   lsrc[4][CAP + 1];
  __shared__ float lew[4][6][CAP + 1];
  __shared__ float lasc[4][6];
  __shared__ float lrr[4][6];
  __shared__ float red[4][384];
  AGG_CORE(feat, off, csr_src, al_s, al_d, order)
  red[sub][c4 + 0] = a0 * rr;
  red[sub][c4 + 1] = a1 * rr;
  red[sub][c4 + 2] = a2 * rr;
  red[sub][c4 + 3] = a3 * rr;
  __syncthreads();
  if (t96 < 16) {
    int c = t96 * 4;
    f32x4 o = (f32x4)0.0f;
#pragma unroll
    for (int hh = 0; hh < HEADS; hh++) {
#pragma unroll
      for (int j = 0; j < 4; j++) o[j] += red[sub][hh * CH + c + j];
    }
#pragma unroll
    for (int j = 0; j < 4; j++) o[j] = o[j] * (1.0f / 6.0f) + b3[c + j];
    *(f32x4*)(out + (size_t)n * CH + c) = o;
  }
}

extern "C" void kernel_launch(void* const* d_in, const int* in_sizes, int n_in,
                              void* d_out, int out_size, void* d_ws, size_t ws_size,
                              hipStream_t stream) {
  const float* x  = (const float*)d_in[0];
  const int*   ei = (const int*)d_in[1];
  const float* W_[4]  = {(const float*)d_in[2], (const float*)d_in[6],
                         (const float*)d_in[10], (const float*)d_in[14]};
  const float* AS_[4] = {(const float*)d_in[3], (const float*)d_in[7],
                         (const float*)d_in[11], (const float*)d_in[15]};
  const float* AD_[4] = {(const float*)d_in[4], (const float*)d_in[8],
                         (const float*)d_in[12], (const float*)d_in[16]};
  const float* B_[4]  = {(const float*)d_in[5], (const float*)d_in[9],
                         (const float*)d_in[13], (const float*)d_in[17]};
  float* out = (float*)d_out;

  // ---- workspace layout ----
  char* w = (char*)d_ws;
  _Float16* feat = (_Float16*)w;                  // [N,384] fp16 GEMM out
  w += (size_t)N_NODES * F_HID * 2;
  char* Apk = w;                                  // fp16 A plane, chunk-major
  w += (size_t)NBM * ATILE3;
  char* Wt0 = w; w += 3 * (size_t)BTILE0;
  char* Wt1 = w; w += 3 * (size_t)BTILE3;
  char* Wt2 = w; w += 3 * (size_t)BTILE3;
  char* Wt3 = w; w += 3 * (size_t)BTILE3;
  float* als = (float*)w; w += (size_t)N_NODES * HEADS * 4;
  float* ald = (float*)w; w += (size_t)N_NODES * HEADS * 4;
  int* off = (int*)w; w += (N_NODES + 1) * 4;
  int* cur = (int*)w; w += N_NODES * 4;
  int* deg = (int*)w; w += N_NODES * 4;   // followed by hcnt[64], zeroed together
  int* hcnt = (int*)w; w += 64 * 4;
  int* hcur = (int*)w; w += 64 * 4;
  int* order = (int*)w; w += N_NODES * 4;
  int* csr = (int*)w;

  // ---- CSR build + degree sort ----
  (void)hipMemsetAsync(deg, 0, (N_NODES + 64) * sizeof(int), stream);  // deg + hcnt
  count_kernel<<<cdiv(N_EDGES, 256), 256, 0, stream>>>(ei, deg);
  scan_kernel<<<1, 256, 0, stream>>>(deg, off, cur);
  scatter_kernel<<<cdiv(N_EDGES, 256), 256, 0, stream>>>(ei, cur, csr);
  bucket_hist<<<cdiv(N_NODES, 256), 256, 0, stream>>>(deg, hcnt);
  bucket_scan<<<1, 64, 0, stream>>>(hcnt, hcur);
  bucket_scatter<<<cdiv(N_NODES, 256), 256, 0, stream>>>(deg, hcur, order);

  // ---- pack inputs (single launch) ----
  convert_all<<<cdiv(NXITEMS + NW0ITEMS + 3 * NWITEMS, 256), 256, 0, stream>>>(
      x, W_[0], W_[1], W_[2], W_[3], Apk, Wt0, Wt1, Wt2, Wt3);

  const int gemm_grid = 8 * cdiv(NBM, 8) * 3;  // XCD-grouped
  const int agg_grid = N_NODES / 4;            // 12500

  // ---- Layer 0 (K=160 packed) ----
  gemm_mfma<K0PAD><<<gemm_grid, 256, 0, stream>>>(Apk, Wt0, AS_[0], AD_[0], als, ald, feat);
  agg_hidden<<<agg_grid, 384, 0, stream>>>(feat, off, csr, als, ald, B_[0], order, Apk);

  // ---- Layers 1,2 (K=384) ----
  gemm_mfma<F_HID><<<gemm_grid, 256, 0, stream>>>(Apk, Wt1, AS_[1], AD_[1], als, ald, feat);
  agg_hidden<<<agg_grid, 384, 0, stream>>>(feat, off, csr, als, ald, B_[1], order, Apk);

  gemm_mfma<F_HID><<<gemm_grid, 256, 0, stream>>>(Apk, Wt2, AS_[2], AD_[2], als, ald, feat);
  agg_hidden<<<agg_grid, 384, 0, stream>>>(feat, off, csr, als, ald, B_[2], order, Apk);

  // ---- Layer 3 (K=384, mean over heads) ----
  gemm_mfma<F_HID><<<gemm_grid, 256, 0, stream>>>(Apk, Wt3, AS_[3], AD_[3], als, ald, feat);
  agg_out<<<agg_grid, 384, 0, stream>>>(feat, off, csr, als, ald, B_[3], order, out);
}

// Round 17
// 592.552 us; speedup vs baseline: 1.6457x; 1.6457x over previous
//
#include <hip/hip_runtime.h>

#define N_NODES 50000
#define M_PAD 50048      // N_NODES rounded up to 128
#define N_EDGES 500000
#define HEADS 6
#define CH 64
#define F_HID 384
#define IN_DIM 131
#define K0PAD 160        // layer-0 K padded to multiple of 32
#define CAP 64           // fast-path max degree
#define NBM 391          // cdiv(N_NODES,128)
#define ATILE3 98304     // (384/32)*8192 bytes per 128-row fp16 A tile
#define ATILE0 40960     // (160/32)*8192
#define BTILE3 98304     // (384/32)*8192 per 128-col fp16 B tile
#define BTILE0 40960

static inline int cdiv(int a, int b) { return (a + b - 1) / b; }

typedef __attribute__((ext_vector_type(4))) float f32x4;
typedef __attribute__((ext_vector_type(8))) _Float16 f16x8;
typedef __attribute__((ext_vector_type(4))) _Float16 f16x4;

__device__ __forceinline__ void gload16(const void* g, void* lds) {
  __builtin_amdgcn_global_load_lds((const __attribute__((address_space(1))) void*)g,
                                   (__attribute__((address_space(3))) void*)lds, 16, 0, 0);
}

// ---------------- CSR build ----------------
__global__ void count_kernel(const int* __restrict__ ei, int* __restrict__ deg) {
  int e = blockIdx.x * blockDim.x + threadIdx.x;
  if (e < N_EDGES) atomicAdd(&deg[ei[N_EDGES + e]], 1);
}

// writes both off (exclusive prefix, +1 shifted) and cur (= off[i], scatter cursors)
__global__ void scan_kernel(const int* __restrict__ deg, int* __restrict__ off,
                            int* __restrict__ cur) {
  __shared__ int sdata[256];
  int tid = threadIdx.x;
  int carry = 0;
  if (tid == 0) off[0] = 0;
  for (int base = 0; base < N_NODES; base += 1024) {
    int idx0 = base + tid * 4;
    int v[4]; int s = 0;
#pragma unroll
    for (int j = 0; j < 4; j++) {
      v[j] = (idx0 + j < N_NODES) ? deg[idx0 + j] : 0;
      s += v[j];
    }
    sdata[tid] = s;
    __syncthreads();
    for (int o = 1; o < 256; o <<= 1) {
      int x = (tid >= o) ? sdata[tid - o] : 0;
      __syncthreads();
      sdata[tid] += x;
      __syncthreads();
    }
    int excl = sdata[tid] - s + carry;
    int total = sdata[255];
    int run = excl;
#pragma unroll
    for (int j = 0; j < 4; j++) {
      if (idx0 + j < N_NODES) cur[idx0 + j] = run;
      run += v[j];
      if (idx0 + j < N_NODES) off[idx0 + j + 1] = run;
    }
    carry += total;
    __syncthreads();
  }
}

__global__ void scatter_kernel(const int* __restrict__ ei, int* __restrict__ cursor,
                               int* __restrict__ csr_src) {
  int e = blockIdx.x * blockDim.x + threadIdx.x;
  if (e < N_EDGES) {
    int d = ei[N_EDGES + e];
    int p = atomicAdd(&cursor[d], 1);
    csr_src[p] = ei[e];
  }
}

// ---------------- unified packer (chunk-major layout) ----------------
#define NXITEMS (M_PAD * (K0PAD / 8))
#define NW0ITEMS (F_HID * (K0PAD / 8))
#define NWITEMS (F_HID * (F_HID / 8))
__global__ void convert_all(const float* __restrict__ x, const float* __restrict__ W0,
                            const float* __restrict__ W1, const float* __restrict__ W2,
                            const float* __restrict__ W3, char* __restrict__ Apk,
                            char* __restrict__ Wt0, char* __restrict__ Wt1,
                            char* __restrict__ Wt2, char* __restrict__ Wt3) {
  int t = blockIdx.x * blockDim.x + threadIdx.x;
  if (t < NXITEMS) {
    const int npc = K0PAD / 8;
    int r = t / npc, g = t % npc;
    int kt = g >> 2, kb = g & 3;
    int k0 = kt * 32 + kb * 8;
    f16x8 hv;
#pragma unroll
    for (int j = 0; j < 8; j++) {
      int k = k0 + j;
      float v = (r < N_NODES && k < IN_DIM) ? x[(long)r * IN_DIM + k] : 0.0f;
      hv[j] = (_Float16)v;
    }
    *(f16x8*)(Apk + (size_t)(r >> 7) * ATILE0 + kt * 8192 + kb * 2048 + (r & 127) * 16) = hv;
  } else if (t < NXITEMS + NW0ITEMS) {
    int u = t - NXITEMS;
    const int npc = K0PAD >> 3;
    int n = u / npc, g = u % npc;
    int kt = g >> 2, kb = g & 3;
    int k0 = kt * 32 + kb * 8;
    f16x8 hv;
#pragma unroll
    for (int j = 0; j < 8; j++) {
      int k = k0 + j;
      float v = (k < IN_DIM) ? W0[(long)k * F_HID + n] : 0.0f;
      hv[j] = (_Float16)v;
    }
    *(f16x8*)(Wt0 + (size_t)(n >> 7) * BTILE0 + kt * 8192 + kb * 2048 + (n & 127) * 16) = hv;
  } else if (t < NXITEMS + NW0ITEMS + 3 * NWITEMS) {
    int u = t - NXITEMS - NW0ITEMS;
    int l = u / NWITEMS;
    u -= l * NWITEMS;
    const float* W = l == 0 ? W1 : (l == 1 ? W2 : W3);
    char* Wt = l == 0 ? Wt1 : (l == 1 ? Wt2 : Wt3);
    const int npc = F_HID >> 3;
    int n = u / npc, g = u % npc;
    int kt = g >> 2, kb = g & 3;
    int k0 = kt * 32 + kb * 8;
    f16x8 hv;
#pragma unroll
    for (int j = 0; j < 8; j++) hv[j] = (_Float16)W[(long)(k0 + j) * F_HID + n];
    *(f16x8*)(Wt + (size_t)(n >> 7) * BTILE3 + kt * 8192 + kb * 2048 + (n & 127) * 16) = hv;
  }
}

// ---------------- fp16 MFMA GEMM + fused attention dots ----------------
template <int K>
__global__ __launch_bounds__(256) void gemm_mfma(const char* __restrict__ Ap,
                                                 const char* __restrict__ Bp,
                                                 const float* __restrict__ AS,
                                                 const float* __restrict__ AD,
                                                 float* __restrict__ als,
                                                 float* __restrict__ ald,
                                                 _Float16* __restrict__ O) {
  constexpr int NKT = K / 32;
  __shared__ __align__(16) char smA[8192];
  __shared__ __align__(16) char smB[8192];
  int xcd = blockIdx.x & 7, slot = blockIdx.x >> 3;
  int bn = slot % 3, tt = slot / 3;
  int bm = tt * 8 + xcd;
  if (bm >= NBM) return;
  int row0 = bm * 128, col0 = bn * 128;
  int tid = threadIdx.x, lane = tid & 63, wv = tid >> 6;
  int wy = wv >> 1, wx = wv & 1;

  f32x4 acc[4][4];
#pragma unroll
  for (int i = 0; i < 4; i++)
#pragma unroll
    for (int j = 0; j < 4; j++) acc[i][j] = (f32x4)0.0f;

  const char* Ab = Ap + (size_t)bm * (NKT * 8192);
  const char* Bb = Bp + (size_t)bn * (NKT * 8192);
  int rsel = lane & 15, ksel = lane >> 4;

  for (int kt = 0; kt < NKT; ++kt) {
#pragma unroll
    for (int i = 0; i < 2; ++i) {
      int b = (i * 4 + wv) * 1024;
      gload16(Ab + (size_t)kt * 8192 + b + lane * 16, smA + b);
      gload16(Bb + (size_t)kt * 8192 + b + lane * 16, smB + b);
    }
    __syncthreads();

    f16x8 av[4], bv[4];
#pragma unroll
    for (int mf = 0; mf < 4; ++mf)
      av[mf] = *(const f16x8*)(smA + ksel * 2048 + (wy * 64 + mf * 16 + rsel) * 16);
#pragma unroll
    for (int nf = 0; nf < 4; ++nf)
      bv[nf] = *(const f16x8*)(smB + ksel * 2048 + (wx * 64 + nf * 16 + rsel) * 16);
#pragma unroll
    for (int mf = 0; mf < 4; ++mf)
#pragma unroll
      for (int nf = 0; nf < 4; ++nf)
        acc[mf][nf] = __builtin_amdgcn_mfma_f32_16x16x32_f16(av[mf], bv[nf], acc[mf][nf], 0, 0, 0);
    __syncthreads();
  }

  int cr = (lane >> 4) * 4, cc = lane & 15;
#pragma unroll
  for (int mf = 0; mf < 4; ++mf)
#pragma unroll
    for (int r = 0; r < 4; ++r) {
      int row = row0 + wy * 64 + mf * 16 + cr + r;
      if (row < N_NODES) {
#pragma unroll
        for (int nf = 0; nf < 4; ++nf)
          O[(size_t)row * F_HID + col0 + wx * 64 + nf * 16 + cc] = (_Float16)acc[mf][nf][r];
      }
    }
  // fused dots: head = 2*bn + wx; this wave holds its full 64 cols
  int head = bn * 2 + wx;
  float sa[4], da[4];
#pragma unroll
  for (int nf = 0; nf < 4; ++nf) {
    sa[nf] = AS[head * CH + nf * 16 + cc];
    da[nf] = AD[head * CH + nf * 16 + cc];
  }
#pragma unroll
  for (int mf = 0; mf < 4; ++mf)
#pragma unroll
    for (int r = 0; r < 4; ++r) {
      float ps = 0.0f, pd = 0.0f;
#pragma unroll
      for (int nf = 0; nf < 4; ++nf) {
        ps += acc[mf][nf][r] * sa[nf];
        pd += acc[mf][nf][r] * da[nf];
      }
#pragma unroll
      for (int o = 1; o < 16; o <<= 1) {
        ps += __shfl_xor(ps, o);
        pd += __shfl_xor(pd, o);
      }
      int row = row0 + wy * 64 + mf * 16 + cr + r;
      if (cc == 0 && row < N_NODES) {
        als[row * HEADS + head] = ps;
        ald[row * HEADS + head] = pd;
      }
    }
}

// ---------------- fused-AB agg core (R13-proven; dead last-chunk barrier removed) ----
typedef __attribute__((ext_vector_type(4))) _Float16 f16x4t;
#define AGG_CORE(FEAT, OFF, CSR, ALS, ALD)                                        \
  int tid = threadIdx.x;                                                          \
  int sub = tid / 96, t96 = tid - sub * 96;                                       \
  int nb = blockIdx.x * 4;                                                        \
  int n = nb + sub;                                                               \
  int c4 = t96 * 4, h = t96 >> 4;                                                 \
  int o_[5];                                                                      \
  _Pragma("unroll")                                                               \
  for (int k = 0; k < 5; ++k) o_[k] = OFF[nb + k];                                \
  int dmax = 0;                                                                   \
  _Pragma("unroll")                                                               \
  for (int k = 0; k < 4; ++k) dmax = max(dmax, o_[k + 1] - o_[k]);                \
  int nch = (dmax + CAP - 1) / CAP; if (nch < 1) nch = 1;                         \
  int s0 = o_[sub], deg = o_[sub + 1] - o_[sub];                                  \
  int pr = tid >> 4, pl = tid & 15;                                               \
  int psub = pr / 6, ph = pr - psub * 6;                                          \
  int ps0 = o_[psub], pdeg = o_[psub + 1] - o_[psub];                             \
  float pad_ = ALD[(nb + psub) * 6 + ph];                                         \
  float m_run = -INFINITY, s_run = 0.0f;                                          \
  float a0 = 0, a1 = 0, a2 = 0, a3 = 0;                                           \
  for (int ch = 0; ch < nch; ++ch) {                                              \
    int base = ch * CAP;                                                          \
    int cl = deg - base; cl = cl < 0 ? 0 : (cl > CAP ? CAP : cl);                 \
    if (t96 < cl) lsrc[sub][t96] = CSR[s0 + base + t96];                          \
    int pcl = pdeg - base; pcl = pcl < 0 ? 0 : (pcl > CAP ? CAP : pcl);           \
    float asc = 1.0f;                                                             \
    if (pcl > 0) {                                                                \
      float mc = -INFINITY;                                                       \
      for (int i = pl; i < pcl; i += 16) {                                        \
        int s = CSR[ps0 + base + i];                                              \
        float e = ALS[s * 6 + ph] + pad_;                                         \
        e = e > 0.0f ? e : 0.2f * e;                                              \
        lew[psub][ph][i] = e;                                                     \
        mc = fmaxf(mc, e);                                                        \
      }                                                                           \
      mc = fmaxf(mc, __shfl_xor(mc, 1));                                          \
      mc = fmaxf(mc, __shfl_xor(mc, 2));                                          \
      mc = fmaxf(mc, __shfl_xor(mc, 4));                                          \
      mc = fmaxf(mc, __shfl_xor(mc, 8));                                          \
      float mn = fmaxf(m_run, mc);                                                \
      asc = (m_run == -INFINITY) ? 0.0f : __expf(m_run - mn);                     \
      float scp = 0.0f;                                                           \
      for (int i = pl; i < pcl; i += 16) {                                        \
        float wv = __expf(lew[psub][ph][i] - mn);                                 \
        lew[psub][ph][i] = wv;                                                    \
        scp += wv;                                                                \
      }                                                                           \
      scp += __shfl_xor(scp, 1);                                                  \
      scp += __shfl_xor(scp, 2);                                                  \
      scp += __shfl_xor(scp, 4);                                                  \
      scp += __shfl_xor(scp, 8);                                                  \
      s_run = s_run * asc + scp;                                                  \
      m_run = mn;                                                                 \
    }                                                                             \
    if (pl == 0) {                                                                \
      lasc[psub][ph] = asc;                                                       \
      if (ch == nch - 1) lrr[psub][ph] = 1.0f / (s_run + 1e-16f);                 \
    }                                                                             \
    __syncthreads();                                                              \
    float cc0 = 0, cc1 = 0, cc2 = 0, cc3 = 0;                                     \
    int i = 0;                                                                    \
    for (; i + 4 <= cl; i += 4) {                                                 \
      int sA = lsrc[sub][i], sB = lsrc[sub][i + 1];                               \
      int sC = lsrc[sub][i + 2], sD = lsrc[sub][i + 3];                           \
      float wA = lew[sub][h][i], wB = lew[sub][h][i + 1];                         \
      float wC = lew[sub][h][i + 2], wD = lew[sub][h][i + 3];                     \
      f16x4t fA = *(const f16x4t*)(FEAT + (size_t)sA * F_HID + c4);               \
      f16x4t fB = *(const f16x4t*)(FEAT + (size_t)sB * F_HID + c4);               \
      f16x4t fC = *(const f16x4t*)(FEAT + (size_t)sC * F_HID + c4);               \
      f16x4t fD = *(const f16x4t*)(FEAT + (size_t)sD * F_HID + c4);               \
      cc0 += wA * (float)fA[0]; cc1 += wA * (float)fA[1];                         \
      cc2 += wA * (float)fA[2]; cc3 += wA * (float)fA[3];                         \
      cc0 += wB * (float)fB[0]; cc1 += wB * (float)fB[1];                         \
      cc2 += wB * (float)fB[2]; cc3 += wB * (float)fB[3];                         \
      cc0 += wC * (float)fC[0]; cc1 += wC * (float)fC[1];                         \
      cc2 += wC * (float)fC[2]; cc3 += wC * (float)fC[3];                         \
      cc0 += wD * (float)fD[0]; cc1 += wD * (float)fD[1];                         \
      cc2 += wD * (float)fD[2]; cc3 += wD * (float)fD[3];                         \
    }                                                                             \
    for (; i < cl; ++i) {                                                         \
      int s = lsrc[sub][i];                                                       \
      float wv = lew[sub][h][i];                                                  \
      f16x4t fv = *(const f16x4t*)(FEAT + (size_t)s * F_HID + c4);                \
      cc0 += wv * (float)fv[0]; cc1 += wv * (float)fv[1];                         \
      cc2 += wv * (float)fv[2]; cc3 += wv * (float)fv[3];                         \
    }                                                                             \
    float asc2 = lasc[sub][h];                                                    \
    a0 = a0 * asc2 + cc0; a1 = a1 * asc2 + cc1;                                   \
    a2 = a2 * asc2 + cc2; a3 = a3 * asc2 + cc3;                                   \
    if (ch + 1 < nch) __syncthreads();  /* WAR fence only between chunks */       \
  }                                                                               \
  float rr = lrr[sub][h];

// hidden layers: normalize + bias + ELU + fp16 pack (chunk-major A plane)
__global__ __launch_bounds__(384) void agg_hidden(const _Float16* __restrict__ feat,
                                                  const int* __restrict__ off,
                                                  const int* __restrict__ csr_src,
                                                  const float* __restrict__ al_s,
                                                  const float* __restrict__ al_d,
                                                  const float* __restrict__ bias,
                                                  char* __restrict__ Apk) {
  __shared__ int   lsrc[4][CAP + 1];
  __shared__ float lew[4][6][CAP + 1];
  __shared__ float lasc[4][6];
  __shared__ float lrr[4][6];
  AGG_CORE(feat, off, csr_src, al_s, al_d)
  float v0 = a0 * rr + bias[c4 + 0];
  float v1 = a1 * rr + bias[c4 + 1];
  float v2 = a2 * rr + bias[c4 + 2];
  float v3 = a3 * rr + bias[c4 + 3];
  v0 = v0 > 0.0f ? v0 : (__expf(v0) - 1.0f);
  v1 = v1 > 0.0f ? v1 : (__expf(v1) - 1.0f);
  v2 = v2 > 0.0f ? v2 : (__expf(v2) - 1.0f);
  v3 = v3 > 0.0f ? v3 : (__expf(v3) - 1.0f);
  f16x4 pv;
  pv[0] = (_Float16)v0; pv[1] = (_Float16)v1;
  pv[2] = (_Float16)v2; pv[3] = (_Float16)v3;
  int kt = c4 >> 5, kb = (c4 >> 3) & 3;
  *(f16x4*)(Apk + (size_t)(n >> 7) * ATILE3 + kt * 8192 + kb * 2048 +
            (n & 127) * 16 + (c4 & 7) * 2) = pv;
}

// output layer: normalize + head-mean + bias
__global__ __launch_bounds__(384) void agg_out(const _Float16* __restrict__ feat,
                                               const int* __restrict__ off,
                                               const int* __restrict__ csr_src,
                                               const float* __restrict__ al_s,
                                               const float* __restrict__ al_d,
                                               const float* __restrict__ b3,
                                               float* __restrict__ out) {
  __shared__ int   lsrc[4][CAP + 1];
  __shared__ float lew[4][6][CAP + 1];
  __shared__ float lasc[4][6];
  __shared__ float lrr[4][6];
  __shared__ float red[4][384];
  AGG_CORE(feat, off, csr_src, al_s, al_d)
  red[sub][c4 + 0] = a0 * rr;
  red[sub][c4 + 1] = a1 * rr;
  red[sub][c4 + 2] = a2 * rr;
  red[sub][c4 + 3] = a3 * rr;
  __syncthreads();
  if (t96 < 16) {
    int c = t96 * 4;
    f32x4 o = (f32x4)0.0f;
#pragma unroll
    for (int hh = 0; hh < HEADS; hh++) {
#pragma unroll
      for (int j = 0; j < 4; j++) o[j] += red[sub][hh * CH + c + j];
    }
#pragma unroll
    for (int j = 0; j < 4; j++) o[j] = o[j] * (1.0f / 6.0f) + b3[c + j];
    *(f32x4*)(out + (size_t)n * CH + c) = o;
  }
}

extern "C" void kernel_launch(void* const* d_in, const int* in_sizes, int n_in,
                              void* d_out, int out_size, void* d_ws, size_t ws_size,
                              hipStream_t stream) {
  const float* x  = (const float*)d_in[0];
  const int*   ei = (const int*)d_in[1];
  const float* W_[4]  = {(const float*)d_in[2], (const float*)d_in[6],
                         (const float*)d_in[10], (const float*)d_in[14]};
  const float* AS_[4] = {(const float*)d_in[3], (const float*)d_in[7],
                         (const float*)d_in[11], (const float*)d_in[15]};
  const float* AD_[4] = {(const float*)d_in[4], (const float*)d_in[8],
                         (const float*)d_in[12], (const float*)d_in[16]};
  const float* B_[4]  = {(const float*)d_in[5], (const float*)d_in[9],
                         (const float*)d_in[13], (const float*)d_in[17]};
  float* out = (float*)d_out;

  // ---- workspace layout ----
  char* w = (char*)d_ws;
  _Float16* feat = (_Float16*)w;                  // [N,384] fp16 GEMM out
  w += (size_t)N_NODES * F_HID * 2;
  char* Apk = w;                                  // fp16 A plane, chunk-major
  w += (size_t)NBM * ATILE3;
  char* Wt0 = w; w += 3 * (size_t)BTILE0;
  char* Wt1 = w; w += 3 * (size_t)BTILE3;
  char* Wt2 = w; w += 3 * (size_t)BTILE3;
  char* Wt3 = w; w += 3 * (size_t)BTILE3;
  float* als = (float*)w; w += (size_t)N_NODES * HEADS * 4;
  float* ald = (float*)w; w += (size_t)N_NODES * HEADS * 4;
  int* off = (int*)w; w += (N_NODES + 1) * 4;
  int* cur = (int*)w; w += N_NODES * 4;
  int* deg = (int*)w; w += N_NODES * 4;
  int* csr = (int*)w;

  // ---- CSR build ----
  (void)hipMemsetAsync(deg, 0, N_NODES * sizeof(int), stream);
  count_kernel<<<cdiv(N_EDGES, 256), 256, 0, stream>>>(ei, deg);
  scan_kernel<<<1, 256, 0, stream>>>(deg, off, cur);
  scatter_kernel<<<cdiv(N_EDGES, 256), 256, 0, stream>>>(ei, cur, csr);

  // ---- pack inputs (single launch) ----
  convert_all<<<cdiv(NXITEMS + NW0ITEMS + 3 * NWITEMS, 256), 256, 0, stream>>>(
      x, W_[0], W_[1], W_[2], W_[3], Apk, Wt0, Wt1, Wt2, Wt3);

  const int gemm_grid = 8 * cdiv(NBM, 8) * 3;  // XCD-grouped
  const int agg_grid = N_NODES / 4;            // 12500

  // ---- Layer 0 (K=160 packed) ----
  gemm_mfma<K0PAD><<<gemm_grid, 256, 0, stream>>>(Apk, Wt0, AS_[0], AD_[0], als, ald, feat);
  agg_hidden<<<agg_grid, 384, 0, stream>>>(feat, off, csr, als, ald, B_[0], Apk);

  // ---- Layers 1,2 (K=384) ----
  gemm_mfma<F_HID><<<gemm_grid, 256, 0, stream>>>(Apk, Wt1, AS_[1], AD_[1], als, ald, feat);
  agg_hidden<<<agg_grid, 384, 0, stream>>>(feat, off, csr, als, ald, B_[1], Apk);

  gemm_mfma<F_HID><<<gemm_grid, 256, 0, stream>>>(Apk, Wt2, AS_[2], AD_[2], als, ald, feat);
  agg_hidden<<<agg_grid, 384, 0, stream>>>(feat, off, csr, als, ald, B_[2], Apk);

  // ---- Layer 3 (K=384, mean over heads) ----
  gemm_mfma<F_HID><<<gemm_grid, 256, 0, stream>>>(Apk, Wt3, AS_[3], AD_[3], als, ald, feat);
  agg_out<<<agg_grid, 384, 0, stream>>>(feat, off, csr, als, ald, B_[3], out);
}

// Round 18
// 518.823 us; speedup vs baseline: 1.8795x; 1.1421x over previous
//
#include <hip/hip_runtime.h>

#define N_NODES 50000
#define M_PAD 50048      // N_NODES rounded up to 128
#define N_EDGES 500000
#define HEADS 6
#define CH 64
#define F_HID 384
#define IN_DIM 131
#define K0PAD 160        // layer-0 K padded to multiple of 32
#define CAP 64           // fast-path max degree
#define NBM 391          // cdiv(N_NODES,128)
#define NSCB 49          // cdiv(N_NODES,1024) scan blocks
#define ATILE3 98304     // (384/32)*8192 bytes per 128-row fp16 A tile
#define ATILE0 40960     // (160/32)*8192
#define BTILE3 98304     // (384/32)*8192 per 128-col fp16 B tile
#define BTILE0 40960

static inline int cdiv(int a, int b) { return (a + b - 1) / b; }

typedef __attribute__((ext_vector_type(4))) float f32x4;
typedef __attribute__((ext_vector_type(8))) _Float16 f16x8;
typedef __attribute__((ext_vector_type(4))) _Float16 f16x4;

__device__ __forceinline__ void gload16(const void* g, void* lds) {
  __builtin_amdgcn_global_load_lds((const __attribute__((address_space(1))) void*)g,
                                   (__attribute__((address_space(3))) void*)lds, 16, 0, 0);
}

// ---------------- CSR build ----------------
__global__ void count_kernel(const int* __restrict__ ei, int* __restrict__ deg) {
  int e = blockIdx.x * blockDim.x + threadIdx.x;
  if (e < N_EDGES) atomicAdd(&deg[ei[N_EDGES + e]], 1);
}

// hierarchical scan, phase 1: per-1024-tile local scan; rel prefix -> cur, totals -> bsum
__global__ void scan1(const int* __restrict__ deg, int* __restrict__ cur,
                      int* __restrict__ bsum) {
  __shared__ int sdata[256];
  int tid = threadIdx.x;
  int idx0 = blockIdx.x * 1024 + tid * 4;
  int v[4]; int s = 0;
#pragma unroll
  for (int j = 0; j < 4; j++) {
    v[j] = (idx0 + j < N_NODES) ? deg[idx0 + j] : 0;
    s += v[j];
  }
  sdata[tid] = s;
  __syncthreads();
  for (int o = 1; o < 256; o <<= 1) {
    int x = (tid >= o) ? sdata[tid - o] : 0;
    __syncthreads();
    sdata[tid] += x;
    __syncthreads();
  }
  int run = sdata[tid] - s;
#pragma unroll
  for (int j = 0; j < 4; j++) {
    if (idx0 + j < N_NODES) cur[idx0 + j] = run;
    run += v[j];
  }
  if (tid == 255) bsum[blockIdx.x] = sdata[255];
}

// phase 2: single-wave exclusive scan of block sums
__global__ void scan2(const int* __restrict__ bsum, int* __restrict__ bpre) {
  int t = threadIdx.x;  // 64 lanes
  int c = (t < NSCB) ? bsum[t] : 0;
  int v = c;
#pragma unroll
  for (int o = 1; o < 64; o <<= 1) {
    int u = __shfl_up(v, o);
    if (t >= o) v += u;
  }
  if (t < NSCB) bpre[t] = v - c;
}

// phase 3: absolute offsets: cur[i] += bpre; off[i+1] = cur[i]+deg[i]; off[0]=0
__global__ void scan3(const int* __restrict__ deg, const int* __restrict__ bpre,
                      int* __restrict__ cur, int* __restrict__ off) {
  int i = blockIdx.x * blockDim.x + threadIdx.x;
  if (i == 0) off[0] = 0;
  if (i < N_NODES) {
    int a = cur[i] + bpre[i >> 10];
    cur[i] = a;
    off[i + 1] = a + deg[i];
  }
}

__global__ void scatter_kernel(const int* __restrict__ ei, int* __restrict__ cursor,
                               int* __restrict__ csr_src) {
  int e = blockIdx.x * blockDim.x + threadIdx.x;
  if (e < N_EDGES) {
    int d = ei[N_EDGES + e];
    int p = atomicAdd(&cursor[d], 1);
    csr_src[p] = ei[e];
  }
}

// ---------------- unified packer (chunk-major layout) ----------------
#define NXITEMS (M_PAD * (K0PAD / 8))
#define NW0ITEMS (F_HID * (K0PAD / 8))
#define NWITEMS (F_HID * (F_HID / 8))
__global__ void convert_all(const float* __restrict__ x, const float* __restrict__ W0,
                            const float* __restrict__ W1, const float* __restrict__ W2,
                            const float* __restrict__ W3, char* __restrict__ Apk,
                            char* __restrict__ Wt0, char* __restrict__ Wt1,
                            char* __restrict__ Wt2, char* __restrict__ Wt3) {
  int t = blockIdx.x * blockDim.x + threadIdx.x;
  if (t < NXITEMS) {
    const int npc = K0PAD / 8;
    int r = t / npc, g = t % npc;
    int kt = g >> 2, kb = g & 3;
    int k0 = kt * 32 + kb * 8;
    f16x8 hv;
#pragma unroll
    for (int j = 0; j < 8; j++) {
      int k = k0 + j;
      float v = (r < N_NODES && k < IN_DIM) ? x[(long)r * IN_DIM + k] : 0.0f;
      hv[j] = (_Float16)v;
    }
    *(f16x8*)(Apk + (size_t)(r >> 7) * ATILE0 + kt * 8192 + kb * 2048 + (r & 127) * 16) = hv;
  } else if (t < NXITEMS + NW0ITEMS) {
    int u = t - NXITEMS;
    const int npc = K0PAD >> 3;
    int n = u / npc, g = u % npc;
    int kt = g >> 2, kb = g & 3;
    int k0 = kt * 32 + kb * 8;
    f16x8 hv;
#pragma unroll
    for (int j = 0; j < 8; j++) {
      int k = k0 + j;
      float v = (k < IN_DIM) ? W0[(long)k * F_HID + n] : 0.0f;
      hv[j] = (_Float16)v;
    }
    *(f16x8*)(Wt0 + (size_t)(n >> 7) * BTILE0 + kt * 8192 + kb * 2048 + (n & 127) * 16) = hv;
  } else if (t < NXITEMS + NW0ITEMS + 3 * NWITEMS) {
    int u = t - NXITEMS - NW0ITEMS;
    int l = u / NWITEMS;
    u -= l * NWITEMS;
    const float* W = l == 0 ? W1 : (l == 1 ? W2 : W3);
    char* Wt = l == 0 ? Wt1 : (l == 1 ? Wt2 : Wt3);
    const int npc = F_HID >> 3;
    int n = u / npc, g = u % npc;
    int kt = g >> 2, kb = g & 3;
    int k0 = kt * 32 + kb * 8;
    f16x8 hv;
#pragma unroll
    for (int j = 0; j < 8; j++) hv[j] = (_Float16)W[(long)(k0 + j) * F_HID + n];
    *(f16x8*)(Wt + (size_t)(n >> 7) * BTILE3 + kt * 8192 + kb * 2048 + (n & 127) * 16) = hv;
  }
}

// ---------------- fp16 MFMA GEMM + fused attention dots ----------------
template <int K>
__global__ __launch_bounds__(256) void gemm_mfma(const char* __restrict__ Ap,
                                                 const char* __restrict__ Bp,
                                                 const float* __restrict__ AS,
                                                 const float* __restrict__ AD,
                                                 float* __restrict__ als,
                                                 float* __restrict__ ald,
                                                 _Float16* __restrict__ O) {
  constexpr int NKT = K / 32;
  __shared__ __align__(16) char smA[8192];
  __shared__ __align__(16) char smB[8192];
  int xcd = blockIdx.x & 7, slot = blockIdx.x >> 3;
  int bn = slot % 3, tt = slot / 3;
  int bm = tt * 8 + xcd;
  if (bm >= NBM) return;
  int row0 = bm * 128, col0 = bn * 128;
  int tid = threadIdx.x, lane = tid & 63, wv = tid >> 6;
  int wy = wv >> 1, wx = wv & 1;

  f32x4 acc[4][4];
#pragma unroll
  for (int i = 0; i < 4; i++)
#pragma unroll
    for (int j = 0; j < 4; j++) acc[i][j] = (f32x4)0.0f;

  const char* Ab = Ap + (size_t)bm * (NKT * 8192);
  const char* Bb = Bp + (size_t)bn * (NKT * 8192);
  int rsel = lane & 15, ksel = lane >> 4;

  for (int kt = 0; kt < NKT; ++kt) {
#pragma unroll
    for (int i = 0; i < 2; ++i) {
      int b = (i * 4 + wv) * 1024;
      gload16(Ab + (size_t)kt * 8192 + b + lane * 16, smA + b);
      gload16(Bb + (size_t)kt * 8192 + b + lane * 16, smB + b);
    }
    __syncthreads();

    f16x8 av[4], bv[4];
#pragma unroll
    for (int mf = 0; mf < 4; ++mf)
      av[mf] = *(const f16x8*)(smA + ksel * 2048 + (wy * 64 + mf * 16 + rsel) * 16);
#pragma unroll
    for (int nf = 0; nf < 4; ++nf)
      bv[nf] = *(const f16x8*)(smB + ksel * 2048 + (wx * 64 + nf * 16 + rsel) * 16);
#pragma unroll
    for (int mf = 0; mf < 4; ++mf)
#pragma unroll
      for (int nf = 0; nf < 4; ++nf)
        acc[mf][nf] = __builtin_amdgcn_mfma_f32_16x16x32_f16(av[mf], bv[nf], acc[mf][nf], 0, 0, 0);
    __syncthreads();
  }

  int cr = (lane >> 4) * 4, cc = lane & 15;
#pragma unroll
  for (int mf = 0; mf < 4; ++mf)
#pragma unroll
    for (int r = 0; r < 4; ++r) {
      int row = row0 + wy * 64 + mf * 16 + cr + r;
      if (row < N_NODES) {
#pragma unroll
        for (int nf = 0; nf < 4; ++nf)
          O[(size_t)row * F_HID + col0 + wx * 64 + nf * 16 + cc] = (_Float16)acc[mf][nf][r];
      }
    }
  // fused dots: head = 2*bn + wx; this wave holds its full 64 cols
  int head = bn * 2 + wx;
  float sa[4], da[4];
#pragma unroll
  for (int nf = 0; nf < 4; ++nf) {
    sa[nf] = AS[head * CH + nf * 16 + cc];
    da[nf] = AD[head * CH + nf * 16 + cc];
  }
#pragma unroll
  for (int mf = 0; mf < 4; ++mf)
#pragma unroll
    for (int r = 0; r < 4; ++r) {
      float ps = 0.0f, pd = 0.0f;
#pragma unroll
      for (int nf = 0; nf < 4; ++nf) {
        ps += acc[mf][nf][r] * sa[nf];
        pd += acc[mf][nf][r] * da[nf];
      }
#pragma unroll
      for (int o = 1; o < 16; o <<= 1) {
        ps += __shfl_xor(ps, o);
        pd += __shfl_xor(pd, o);
      }
      int row = row0 + wy * 64 + mf * 16 + cr + r;
      if (cc == 0 && row < N_NODES) {
        als[row * HEADS + head] = ps;
        ald[row * HEADS + head] = pd;
      }
    }
}

// ---------------- fused-AB agg core (R17-proven) ----------------
typedef __attribute__((ext_vector_type(4))) _Float16 f16x4t;
#define AGG_CORE(FEAT, OFF, CSR, ALS, ALD)                                        \
  int tid = threadIdx.x;                                                          \
  int sub = tid / 96, t96 = tid - sub * 96;                                       \
  int nb = blockIdx.x * 4;                                                        \
  int n = nb + sub;                                                               \
  int c4 = t96 * 4, h = t96 >> 4;                                                 \
  int o_[5];                                                                      \
  _Pragma("unroll")                                                               \
  for (int k = 0; k < 5; ++k) o_[k] = OFF[nb + k];                                \
  int dmax = 0;                                                                   \
  _Pragma("unroll")                                                               \
  for (int k = 0; k < 4; ++k) dmax = max(dmax, o_[k + 1] - o_[k]);                \
  int nch = (dmax + CAP - 1) / CAP; if (nch < 1) nch = 1;                         \
  int s0 = o_[sub], deg = o_[sub + 1] - o_[sub];                                  \
  int pr = tid >> 4, pl = tid & 15;                                               \
  int psub = pr / 6, ph = pr - psub * 6;                                          \
  int ps0 = o_[psub], pdeg = o_[psub + 1] - o_[psub];                             \
  float pad_ = ALD[(nb + psub) * 6 + ph];                                         \
  float m_run = -INFINITY, s_run = 0.0f;                                          \
  float a0 = 0, a1 = 0, a2 = 0, a3 = 0;                                           \
  for (int ch = 0; ch < nch; ++ch) {                                              \
    int base = ch * CAP;                                                          \
    int cl = deg - base; cl = cl < 0 ? 0 : (cl > CAP ? CAP : cl);                 \
    if (t96 < cl) lsrc[sub][t96] = CSR[s0 + base + t96];                          \
    int pcl = pdeg - base; pcl = pcl < 0 ? 0 : (pcl > CAP ? CAP : pcl);           \
    float asc = 1.0f;                                                             \
    if (pcl > 0) {                                                                \
      float mc = -INFINITY;                                                       \
      for (int i = pl; i < pcl; i += 16) {                                        \
        int s = CSR[ps0 + base + i];                                              \
        float e = ALS[s * 6 + ph] + pad_;                                         \
        e = e > 0.0f ? e : 0.2f * e;                                              \
        lew[psub][ph][i] = e;                                                     \
        mc = fmaxf(mc, e);                                                        \
      }                                                                           \
      mc = fmaxf(mc, __shfl_xor(mc, 1));                                          \
      mc = fmaxf(mc, __shfl_xor(mc, 2));                                          \
      mc = fmaxf(mc, __shfl_xor(mc, 4));                                          \
      mc = fmaxf(mc, __shfl_xor(mc, 8));                                          \
      float mn = fmaxf(m_run, mc);                                                \
      asc = (m_run == -INFINITY) ? 0.0f : __expf(m_run - mn);                     \
      float scp = 0.0f;                                                           \
      for (int i = pl; i < pcl; i += 16) {                                        \
        float wv = __expf(lew[psub][ph][i] - mn);                                 \
        lew[psub][ph][i] = wv;                                                    \
        scp += wv;                                                                \
      }                                                                           \
      scp += __shfl_xor(scp, 1);                                                  \
      scp += __shfl_xor(scp, 2);                                                  \
      scp += __shfl_xor(scp, 4);                                                  \
      scp += __shfl_xor(scp, 8);                                                  \
      s_run = s_run * asc + scp;                                                  \
      m_run = mn;                                                                 \
    }                                                                             \
    if (pl == 0) {                                                                \
      lasc[psub][ph] = asc;                                                       \
      if (ch == nch - 1) lrr[psub][ph] = 1.0f / (s_run + 1e-16f);                 \
    }                                                                             \
    __syncthreads();                                                              \
    float cc0 = 0, cc1 = 0, cc2 = 0, cc3 = 0;                                     \
    int i = 0;                                                                    \
    for (; i + 4 <= cl; i += 4) {                                                 \
      int sA = lsrc[sub][i], sB = lsrc[sub][i + 1];                               \
      int sC = lsrc[sub][i + 2], sD = lsrc[sub][i + 3];                           \
      float wA = lew[sub][h][i], wB = lew[sub][h][i + 1];                         \
      float wC = lew[sub][h][i + 2], wD = lew[sub][h][i + 3];                     \
      f16x4t fA = *(const f16x4t*)(FEAT + (size_t)sA * F_HID + c4);               \
      f16x4t fB = *(const f16x4t*)(FEAT + (size_t)sB * F_HID + c4);               \
      f16x4t fC = *(const f16x4t*)(FEAT + (size_t)sC * F_HID + c4);               \
      f16x4t fD = *(const f16x4t*)(FEAT + (size_t)sD * F_HID + c4);               \
      cc0 += wA * (float)fA[0]; cc1 += wA * (float)fA[1];                         \
      cc2 += wA * (float)fA[2]; cc3 += wA * (float)fA[3];                         \
      cc0 += wB * (float)fB[0]; cc1 += wB * (float)fB[1];                         \
      cc2 += wB * (float)fB[2]; cc3 += wB * (float)fB[3];                         \
      cc0 += wC * (float)fC[0]; cc1 += wC * (float)fC[1];                         \
      cc2 += wC * (float)fC[2]; cc3 += wC * (float)fC[3];                         \
      cc0 += wD * (float)fD[0]; cc1 += wD * (float)fD[1];                         \
      cc2 += wD * (float)fD[2]; cc3 += wD * (float)fD[3];                         \
    }                                                                             \
    for (; i < cl; ++i) {                                                         \
      int s = lsrc[sub][i];                                                       \
      float wv = lew[sub][h][i];                                                  \
      f16x4t fv = *(const f16x4t*)(FEAT + (size_t)s * F_HID + c4);                \
      cc0 += wv * (float)fv[0]; cc1 += wv * (float)fv[1];                         \
      cc2 += wv * (float)fv[2]; cc3 += wv * (float)fv[3];                         \
    }                                                                             \
    float asc2 = lasc[sub][h];                                                    \
    a0 = a0 * asc2 + cc0; a1 = a1 * asc2 + cc1;                                   \
    a2 = a2 * asc2 + cc2; a3 = a3 * asc2 + cc3;                                   \
    if (ch + 1 < nch) __syncthreads();  /* WAR fence only between chunks */       \
  }                                                                               \
  float rr = lrr[sub][h];

// hidden layers: normalize + bias + ELU + fp16 pack (chunk-major A plane)
__global__ __launch_bounds__(384) void agg_hidden(const _Float16* __restrict__ feat,
                                                  const int* __restrict__ off,
                                                  const int* __restrict__ csr_src,
                                                  const float* __restrict__ al_s,
                                                  const float* __restrict__ al_d,
                                                  const float* __restrict__ bias,
                                                  char* __restrict__ Apk) {
  __shared__ int   lsrc[4][CAP + 1];
  __shared__ float lew[4][6][CAP + 1];
  __shared__ float lasc[4][6];
  __shared__ float lrr[4][6];
  AGG_CORE(feat, off, csr_src, al_s, al_d)
  float v0 = a0 * rr + bias[c4 + 0];
  float v1 = a1 * rr + bias[c4 + 1];
  float v2 = a2 * rr + bias[c4 + 2];
  float v3 = a3 * rr + bias[c4 + 3];
  v0 = v0 > 0.0f ? v0 : (__expf(v0) - 1.0f);
  v1 = v1 > 0.0f ? v1 : (__expf(v1) - 1.0f);
  v2 = v2 > 0.0f ? v2 : (__expf(v2) - 1.0f);
  v3 = v3 > 0.0f ? v3 : (__expf(v3) - 1.0f);
  f16x4 pv;
  pv[0] = (_Float16)v0; pv[1] = (_Float16)v1;
  pv[2] = (_Float16)v2; pv[3] = (_Float16)v3;
  int kt = c4 >> 5, kb = (c4 >> 3) & 3;
  *(f16x4*)(Apk + (size_t)(n >> 7) * ATILE3 + kt * 8192 + kb * 2048 +
            (n & 127) * 16 + (c4 & 7) * 2) = pv;
}

// output layer: normalize + head-mean + bias
__global__ __launch_bounds__(384) void agg_out(const _Float16* __restrict__ feat,
                                               const int* __restrict__ off,
                                               const int* __restrict__ csr_src,
                                               const float* __restrict__ al_s,
                                               const float* __restrict__ al_d,
                                               const float* __restrict__ b3,
                                               float* __restrict__ out) {
  __shared__ int   lsrc[4][CAP + 1];
  __shared__ float lew[4][6][CAP + 1];
  __shared__ float lasc[4][6];
  __shared__ float lrr[4][6];
  __shared__ float red[4][384];
  AGG_CORE(feat, off, csr_src, al_s, al_d)
  red[sub][c4 + 0] = a0 * rr;
  red[sub][c4 + 1] = a1 * rr;
  red[sub][c4 + 2] = a2 * rr;
  red[sub][c4 + 3] = a3 * rr;
  __syncthreads();
  if (t96 < 16) {
    int c = t96 * 4;
    f32x4 o = (f32x4)0.0f;
#pragma unroll
    for (int hh = 0; hh < HEADS; hh++) {
#pragma unroll
      for (int j = 0; j < 4; j++) o[j] += red[sub][hh * CH + c + j];
    }
#pragma unroll
    for (int j = 0; j < 4; j++) o[j] = o[j] * (1.0f / 6.0f) + b3[c + j];
    *(f32x4*)(out + (size_t)n * CH + c) = o;
  }
}

extern "C" void kernel_launch(void* const* d_in, const int* in_sizes, int n_in,
                              void* d_out, int out_size, void* d_ws, size_t ws_size,
                              hipStream_t stream) {
  const float* x  = (const float*)d_in[0];
  const int*   ei = (const int*)d_in[1];
  const float* W_[4]  = {(const float*)d_in[2], (const float*)d_in[6],
                         (const float*)d_in[10], (const float*)d_in[14]};
  const float* AS_[4] = {(const float*)d_in[3], (const float*)d_in[7],
                         (const float*)d_in[11], (const float*)d_in[15]};
  const float* AD_[4] = {(const float*)d_in[4], (const float*)d_in[8],
                         (const float*)d_in[12], (const float*)d_in[16]};
  const float* B_[4]  = {(const float*)d_in[5], (const float*)d_in[9],
                         (const float*)d_in[13], (const float*)d_in[17]};
  float* out = (float*)d_out;

  // ---- workspace layout ----
  char* w = (char*)d_ws;
  _Float16* feat = (_Float16*)w;                  // [N,384] fp16 GEMM out
  w += (size_t)N_NODES * F_HID * 2;
  char* Apk = w;                                  // fp16 A plane, chunk-major
  w += (size_t)NBM * ATILE3;
  char* Wt0 = w; w += 3 * (size_t)BTILE0;
  char* Wt1 = w; w += 3 * (size_t)BTILE3;
  char* Wt2 = w; w += 3 * (size_t)BTILE3;
  char* Wt3 = w; w += 3 * (size_t)BTILE3;
  float* als = (float*)w; w += (size_t)N_NODES * HEADS * 4;
  float* ald = (float*)w; w += (size_t)N_NODES * HEADS * 4;
  int* off = (int*)w; w += (N_NODES + 1) * 4;
  int* cur = (int*)w; w += N_NODES * 4;
  int* deg = (int*)w; w += N_NODES * 4;
  int* bsum = (int*)w; w += 64 * 4;
  int* bpre = (int*)w; w += 64 * 4;
  int* csr = (int*)w;

  // ---- CSR build (hierarchical scan) ----
  (void)hipMemsetAsync(deg, 0, N_NODES * sizeof(int), stream);
  count_kernel<<<cdiv(N_EDGES, 256), 256, 0, stream>>>(ei, deg);
  scan1<<<NSCB, 256, 0, stream>>>(deg, cur, bsum);
  scan2<<<1, 64, 0, stream>>>(bsum, bpre);
  scan3<<<cdiv(N_NODES, 256), 256, 0, stream>>>(deg, bpre, cur, off);
  scatter_kernel<<<cdiv(N_EDGES, 256), 256, 0, stream>>>(ei, cur, csr);

  // ---- pack inputs (single launch) ----
  convert_all<<<cdiv(NXITEMS + NW0ITEMS + 3 * NWITEMS, 256), 256, 0, stream>>>(
      x, W_[0], W_[1], W_[2], W_[3], Apk, Wt0, Wt1, Wt2, Wt3);

  const int gemm_grid = 8 * cdiv(NBM, 8) * 3;  // XCD-grouped
  const int agg_grid = N_NODES / 4;            // 12500

  // ---- Layer 0 (K=160 packed) ----
  gemm_mfma<K0PAD><<<gemm_grid, 256, 0, stream>>>(Apk, Wt0, AS_[0], AD_[0], als, ald, feat);
  agg_hidden<<<agg_grid, 384, 0, stream>>>(feat, off, csr, als, ald, B_[0], Apk);

  // ---- Layers 1,2 (K=384) ----
  gemm_mfma<F_HID><<<gemm_grid, 256, 0, stream>>>(Apk, Wt1, AS_[1], AD_[1], als, ald, feat);
  agg_hidden<<<agg_grid, 384, 0, stream>>>(feat, off, csr, als, ald, B_[1], Apk);

  gemm_mfma<F_HID><<<gemm_grid, 256, 0, stream>>>(Apk, Wt2, AS_[2], AD_[2], als, ald, feat);
  agg_hidden<<<agg_grid, 384, 0, stream>>>(feat, off, csr, als, ald, B_[2], Apk);

  // ---- Layer 3 (K=384, mean over heads) ----
  gemm_mfma<F_HID><<<gemm_grid, 256, 0, stream>>>(Apk, Wt3, AS_[3], AD_[3], als, ald, feat);
  agg_out<<<agg_grid, 384, 0, stream>>>(feat, off, csr, als, ald, B_[3], out);
}